// Round 1
// baseline (1125.377 us; speedup 1.0000x reference)
//
#include <hip/hip_runtime.h>
#include <hip/hip_bf16.h>
#include <stdint.h>

// Problem constants (fixed by the reference file)
#define B_  8192
#define L_  2048
#define NF_ 8

typedef __bf16 bf16_t;
typedef __bf16 bf16x8 __attribute__((ext_vector_type(8)));
typedef __bf16 bf16x4 __attribute__((ext_vector_type(4)));
typedef float  floatx4 __attribute__((ext_vector_type(4)));

// fp32 -> bf16 round-to-nearest-even
__device__ __forceinline__ bf16_t f2bf(float f) {
    union { float f; uint32_t u; } a; a.f = f;
    uint32_t r = a.u + 0x7fffu + ((a.u >> 16) & 1u);
    union { uint16_t s; bf16_t b; } o; o.s = (uint16_t)(r >> 16);
    return o.b;
}

// async global->LDS, 16B per lane. LDS dest is wave-uniform base + lane*16.
#define GLD16(gp, lp)                                                          \
    __builtin_amdgcn_global_load_lds(                                          \
        (const __attribute__((address_space(1))) void*)(gp),                   \
        (__attribute__((address_space(3))) void*)(lp), 16, 0, 0)

// ---------------------------------------------------------------------------
// fp32 -> bf16 bulk conversion. One float4 per thread.
// ---------------------------------------------------------------------------
__global__ __launch_bounds__(256) void cvt_kernel(const float* __restrict__ s,
                                                  bf16_t* __restrict__ d) {
    const int i = blockIdx.x * 256 + threadIdx.x;
    float4 f = ((const float4*)s)[i];
    bf16x4 o = { f2bf(f.x), f2bf(f.y), f2bf(f.z), f2bf(f.w) };
    ((bf16x4*)d)[i] = o;
}

// ---------------------------------------------------------------------------
// Vb[M,N] = bf16( A[M,K] * W[N,K]^T + bias ).  M=8192, N=K=2048.
//
// 256x256 tile, 512 threads = 8 waves (2 x 4), per-wave output 128x64.
// K is processed in 64 tiles of BK=32 through a RING OF 4 LDS buffers
// (slot = A[256][32] | B[256][32] = 32 KB; 4 slots = 128 KB).
//
// Deep pipeline (counted vmcnt, never 0 in steady state):
//   prologue: stage tiles 0,1,2 (12 loads) ; vmcnt(8) ; barrier
//   tile t:   phase A: stage A-half of t+3 | ds_read 8 | barrier |
//             setprio(1) 16 MFMA setprio(0) | barrier
//             phase B: stage B-half of t+3 | ds_read 4 | barrier |
//             setprio(1) 16 MFMA setprio(0) | vmcnt(8) | barrier
//   Slot (t+3)&3 was last READ in tile t-1 (all reads consumed before the
//   t-1 -> t boundary barrier), so staging into it during tile t is race-free.
//   At the boundary, outstanding = tiles t+1,t+2,t+3 = 12 loads; vmcnt(8)
//   retires exactly tile t+1 -> 2-tiles-deep prefetch stays in flight.
//
// LDS swizzle: row r (32 bf16 = 4 chunks of 16B): logical chunk c lives at
// physical chunk c ^ ((r>>1)&3).  ds_read_b128 by 16 consecutive lanes
// (consecutive rows, fixed c) then hits all 8 bank-groups 2-way (free).
// global_load_lds writes linearly, so the SOURCE address is pre-swizzled
// (lane stages slot s: row=s>>2, phys chunk=s&3 -> logical chunk
// (s&3)^((s>>3)&3), which is invariant across the +128-row second load).
// ---------------------------------------------------------------------------
#define VM8  asm volatile("s_waitcnt vmcnt(8)" ::: "memory")
#define VM4  asm volatile("s_waitcnt vmcnt(4)" ::: "memory")
#define VM0  asm volatile("s_waitcnt vmcnt(0)" ::: "memory")
#define VMX  do {} while (0)

__global__ __launch_bounds__(512, 2) void gemm_bt_kernel(
    const bf16_t* __restrict__ A,   // [M, K]
    const bf16_t* __restrict__ W,   // [N, K]
    const float*  __restrict__ bias,// [N]
    bf16_t* __restrict__ Vb)        // [M, N] bf16 (also next A)
{
    constexpr int K  = L_;
    constexpr int N  = L_;
    constexpr int NT = K / 32;                  // 64 K-tiles
    __shared__ alignas(16) bf16_t lds[4][16384]; // slot: A 8192 | B 8192 elems

    const int tid  = threadIdx.x;
    const int lane = tid & 63;
    const int wave = tid >> 6;
    const int wm   = wave >> 2;   // 0..1
    const int wn   = wave & 3;    // 0..3
    const int tm   = blockIdx.y * 256;
    const int tn   = blockIdx.x * 256;

    // --- staging: thread stages 16B slots {tid, tid+512} of A and of B ---
    const int r0 = tid >> 2;                          // staging row (0..127)
    const int lc = (tid & 3) ^ ((tid >> 3) & 3);      // logical chunk (swz)
    const bf16_t* Ag = A + (size_t)(tm + r0) * K + lc * 8;
    const bf16_t* Wg = W + (size_t)(tn + r0) * K + lc * 8;
    const int dA = tid * 8;                           // elems within slot
    const int dB = 8192 + tid * 8;

    // --- ds_read fragment offsets ---
    const int l15 = lane & 15;
    const int pq  = (((lane >> 4) ^ ((lane >> 1) & 3))) * 8; // phys chunk * 8
    const int aOff = (wm * 128 + l15) * 32 + pq;
    const int bOff = 8192 + (wn * 64 + l15) * 32 + pq;

    floatx4 acc[8][4] = {};

    auto stageA = [&](int u) {
        bf16_t* d = &lds[u & 3][dA];
        const bf16_t* g = Ag + u * 32;
        GLD16(g, d);
        GLD16(g + (size_t)128 * K, d + 4096);
    };
    auto stageB = [&](int u) {
        bf16_t* d = &lds[u & 3][dB];
        const bf16_t* g = Wg + u * 32;
        GLD16(g, d);
        GLD16(g + (size_t)128 * K, d + 4096);
    };

    // prologue: tiles 0,1,2 in flight
    stageA(0); stageB(0);
    stageA(1); stageB(1);
    stageA(2); stageB(2);
    VM8;
    asm volatile("s_barrier" ::: "memory");

#define TILE_BODY(T, STG, VMCB)                                                \
    {                                                                          \
        const int t_ = (T);                                                    \
        const bf16_t* sl = &lds[t_ & 3][0];                                    \
        bf16x8 af[4], bw[4];                                                   \
        /* ---- phase A: mi 0-3 ---- */                                        \
        if (STG) stageA(t_ + 3);                                               \
        _Pragma("unroll")                                                      \
        for (int mi = 0; mi < 4; ++mi)                                         \
            af[mi] = *(const bf16x8*)(sl + aOff + mi * 512);                   \
        _Pragma("unroll")                                                      \
        for (int ni = 0; ni < 4; ++ni)                                         \
            bw[ni] = *(const bf16x8*)(sl + bOff + ni * 512);                   \
        asm volatile("s_barrier" ::: "memory");                                \
        __builtin_amdgcn_sched_barrier(0);                                     \
        __builtin_amdgcn_s_setprio(1);                                         \
        _Pragma("unroll")                                                      \
        for (int mi = 0; mi < 4; ++mi)                                         \
            _Pragma("unroll")                                                  \
            for (int ni = 0; ni < 4; ++ni)                                     \
                acc[mi][ni] = __builtin_amdgcn_mfma_f32_16x16x32_bf16(         \
                    af[mi], bw[ni], acc[mi][ni], 0, 0, 0);                     \
        __builtin_amdgcn_s_setprio(0);                                         \
        asm volatile("s_barrier" ::: "memory");                                \
        /* ---- phase B: mi 4-7 (bw reused from registers) ---- */             \
        if (STG) stageB(t_ + 3);                                               \
        _Pragma("unroll")                                                      \
        for (int mi = 0; mi < 4; ++mi)                                         \
            af[mi] = *(const bf16x8*)(sl + aOff + (mi + 4) * 512);             \
        asm volatile("s_barrier" ::: "memory");                                \
        __builtin_amdgcn_sched_barrier(0);                                     \
        __builtin_amdgcn_s_setprio(1);                                         \
        _Pragma("unroll")                                                      \
        for (int mi = 0; mi < 4; ++mi)                                         \
            _Pragma("unroll")                                                  \
            for (int ni = 0; ni < 4; ++ni)                                     \
                acc[mi + 4][ni] = __builtin_amdgcn_mfma_f32_16x16x32_bf16(     \
                    af[mi], bw[ni], acc[mi + 4][ni], 0, 0, 0);                 \
        __builtin_amdgcn_s_setprio(0);                                         \
        VMCB;                                                                  \
        asm volatile("s_barrier" ::: "memory");                                \
    }

    for (int t = 0; t < NT - 3; ++t) TILE_BODY(t, 1, VM8);
    TILE_BODY(NT - 3, 0, VM4);
    TILE_BODY(NT - 2, 0, VM0);
    TILE_BODY(NT - 1, 0, VMX);
#undef TILE_BODY

    // epilogue: C/D layout col = lane&15, row = (lane>>4)*4 + reg
    const int row0 = tm + wm * 128 + (lane >> 4) * 4;
    const int col0 = tn + wn * 64 + l15;
#pragma unroll
    for (int ni = 0; ni < 4; ++ni) {
        const int col = col0 + ni * 16;
        const float bv = bias[col];
#pragma unroll
        for (int mi = 0; mi < 8; ++mi) {
#pragma unroll
            for (int r = 0; r < 4; ++r) {
                Vb[(size_t)(row0 + mi * 16 + r) * N + col] = f2bf(acc[mi][ni][r] + bv);
            }
        }
    }
}

// ---------------------------------------------------------------------------
// Householder reflection: z -= 2 v (v.z)/(v.v). ONE WAVE PER ROW (no LDS,
// no __syncthreads). 256-thread block = 4 rows. Butterfly shfl_xor reduce.
// v chunk j = elements 8*(lane+64j) .. +8  <->  z4[2*(lane+64j)], z4[2*(lane+64j)+1]
// ---------------------------------------------------------------------------
__global__ __launch_bounds__(256, 4) void hflow_kernel(
    const bf16_t* __restrict__ V, const float* __restrict__ zin,
    float* __restrict__ zout)
{
    const int lane = threadIdx.x & 63;
    const int row  = blockIdx.x * 4 + (threadIdx.x >> 6);
    const bf16x8* v8 = (const bf16x8*)(V + (size_t)row * L_);
    const float4* z4 = (const float4*)(zin + (size_t)row * L_);
    float4*       zo = (float4*)(zout + (size_t)row * L_);

    bf16x8 v[4];
    float4 z[8];
#pragma unroll
    for (int j = 0; j < 4; ++j) {
        const int idx = lane + 64 * j;
        v[j]         = v8[idx];
        z[2 * j]     = z4[2 * idx];
        z[2 * j + 1] = z4[2 * idx + 1];
    }

    float vf[32];
#pragma unroll
    for (int j = 0; j < 4; ++j)
#pragma unroll
        for (int e = 0; e < 8; ++e) vf[j * 8 + e] = (float)v[j][e];

    float vz = 0.f, vv = 0.f;
#pragma unroll
    for (int j = 0; j < 4; ++j) {
        const float* f = vf + j * 8;
        vz += f[0] * z[2*j].x + f[1] * z[2*j].y + f[2] * z[2*j].z + f[3] * z[2*j].w
            + f[4] * z[2*j+1].x + f[5] * z[2*j+1].y + f[6] * z[2*j+1].z + f[7] * z[2*j+1].w;
        vv += f[0]*f[0] + f[1]*f[1] + f[2]*f[2] + f[3]*f[3]
            + f[4]*f[4] + f[5]*f[5] + f[6]*f[6] + f[7]*f[7];
    }

#pragma unroll
    for (int off = 1; off < 64; off <<= 1) {
        vz += __shfl_xor(vz, off);
        vv += __shfl_xor(vv, off);
    }
    const float s = 2.0f * vz / vv;

#pragma unroll
    for (int j = 0; j < 4; ++j) {
        const int idx = lane + 64 * j;
        const float* f = vf + j * 8;
        float4 a = z[2*j], b = z[2*j+1];
        a.x -= s * f[0]; a.y -= s * f[1]; a.z -= s * f[2]; a.w -= s * f[3];
        b.x -= s * f[4]; b.y -= s * f[5]; b.z -= s * f[6]; b.w -= s * f[7];
        zo[2 * idx]     = a;
        zo[2 * idx + 1] = b;
    }
}

// ---------------------------------------------------------------------------
extern "C" void kernel_launch(void* const* d_in, const int* in_sizes, int n_in,
                              void* d_out, int out_size, void* d_ws, size_t ws_size,
                              hipStream_t stream) {
    (void)in_sizes; (void)n_in; (void)out_size; (void)ws_size;
    const float* z_in   = (const float*)d_in[0];  // [B, L]
    const float* h_last = (const float*)d_in[1];  // [B, H]
    const float* W0     = (const float*)d_in[2];  // [L, H]
    const float* b0     = (const float*)d_in[3];  // [L]
    const float* Wsp    = (const float*)d_in[4];  // [NF-1, L, L]
    const float* bsp    = (const float*)d_in[5];  // [NF-1, L]
    float* z_out = (float*)d_out;

    // workspace: bf16 weights (all 8) | bf16 V ping | bf16 V pong
    char* ws = (char*)d_ws;
    bf16_t* Wbf = (bf16_t*)ws;                                        // NF*L*L
    bf16_t* Vp0 = (bf16_t*)(ws + (size_t)NF_ * L_ * L_ * 2);          // B*L
    bf16_t* Vp1 = Vp0 + (size_t)B_ * L_;                              // B*L

    cvt_kernel<<<(L_ * L_) / 1024, 256, 0, stream>>>(W0, Wbf);
    cvt_kernel<<<((NF_ - 1) * L_ * L_) / 1024, 256, 0, stream>>>(
        Wsp, Wbf + (size_t)L_ * L_);
    cvt_kernel<<<(B_ * L_) / 1024, 256, 0, stream>>>(h_last, Vp0);

    dim3 ggrid(L_ / 256, B_ / 256);
    bf16_t* bufs[2] = { Vp0, Vp1 };
    for (int j = 0; j < NF_; ++j) {
        const float* bias = (j == 0) ? b0 : bsp + (size_t)(j - 1) * L_;
        const bf16_t* Wj = Wbf + (size_t)j * L_ * L_;
        bf16_t* Ain = bufs[j & 1];
        bf16_t* Vout = bufs[(j + 1) & 1];
        gemm_bt_kernel<<<ggrid, 512, 0, stream>>>(Ain, Wj, bias, Vout);
        hflow_kernel<<<B_ / 4, 256, 0, stream>>>(
            Vout, (j == 0) ? z_in : z_out, z_out);
    }
}

// Round 2
// 889.123 us; speedup vs baseline: 1.2657x; 1.2657x over previous
//
#include <hip/hip_runtime.h>
#include <hip/hip_bf16.h>
#include <stdint.h>

// Problem constants (fixed by the reference file)
#define B_  8192
#define L_  2048
#define NF_ 8

typedef __bf16 bf16_t;
typedef __bf16 bf16x8 __attribute__((ext_vector_type(8)));
typedef __bf16 bf16x4 __attribute__((ext_vector_type(4)));
typedef float  floatx4 __attribute__((ext_vector_type(4)));

// fp32 -> bf16 round-to-nearest-even
__device__ __forceinline__ bf16_t f2bf(float f) {
    union { float f; uint32_t u; } a; a.f = f;
    uint32_t r = a.u + 0x7fffu + ((a.u >> 16) & 1u);
    union { uint16_t s; bf16_t b; } o; o.s = (uint16_t)(r >> 16);
    return o.b;
}

// async global->LDS, 16B per lane. LDS dest is wave-uniform base + lane*16.
#define GLD16(gp, lp)                                                          \
    __builtin_amdgcn_global_load_lds(                                          \
        (const __attribute__((address_space(1))) void*)(gp),                   \
        (__attribute__((address_space(3))) void*)(lp), 16, 0, 0)

// ---------------------------------------------------------------------------
// fp32 -> bf16 bulk conversion. One float4 per thread.
// ---------------------------------------------------------------------------
__global__ __launch_bounds__(256) void cvt_kernel(const float* __restrict__ s,
                                                  bf16_t* __restrict__ d) {
    const int i = blockIdx.x * 256 + threadIdx.x;
    float4 f = ((const float4*)s)[i];
    bf16x4 o = { f2bf(f.x), f2bf(f.y), f2bf(f.z), f2bf(f.w) };
    ((bf16x4*)d)[i] = o;
}

// ---------------------------------------------------------------------------
// Vb[M,N] = bf16( A[M,K] * W[N,K]^T + bias )   (bf16 in, bf16 out)
// M=8192, N=K=2048. 128x128 tile, BK=64 (32 MFMA/wave per barrier),
// 256 threads = 4 waves, each wave a 64x64 subtile as 4x4 MFMA 16x16x32.
// (Round-0 verified structure: 74.5 us, ~922 TF. The 256x256 deep-pipeline
// variant regressed to 89.7 us at 1 block/CU — reverted.)
//
// LDS swizzle (rows of 8 x 16B chunks): logical (row r, chunk c) lives at
// physical slot r*8 + (c ^ (r&7)). ds_read_b128: any 8 consecutive lanes read
// 8 consecutive rows at fixed c -> 8 distinct slot%8 -> conflict-free.
// Staging slot s = tid + i*256: r=(tid>>3)+32i, p=tid&7, so the logical chunk
// c = (tid&7) ^ ((tid>>3)&7) is i-invariant -> one base pointer per thread.
// ---------------------------------------------------------------------------
__global__ __launch_bounds__(256, 4) void gemm_bt_kernel(
    const bf16_t* __restrict__ A,   // [M, K]
    const bf16_t* __restrict__ W,   // [N, K]
    const float*  __restrict__ bias,// [N]
    bf16_t* __restrict__ Vb)        // [M, N] bf16 (also next A)
{
    constexpr int K = L_;
    constexpr int N = L_;
    __shared__ alignas(16) bf16_t sA[128 * 64];
    __shared__ alignas(16) bf16_t sB[128 * 64];

    const int tid  = threadIdx.x;
    const int lane = tid & 63;
    const int wave = tid >> 6;
    const int wm   = wave >> 1;   // 0..1
    const int wn   = wave & 1;    // 0..1
    const int tm   = blockIdx.y * 128;
    const int tn   = blockIdx.x * 128;

    const int srow = tid >> 3;
    const int schk = (tid & 7) ^ (srow & 7);
    const bf16_t* Ag = A + (size_t)(tm + srow) * K + schk * 8;
    const bf16_t* Wg = W + (size_t)(tn + srow) * K + schk * 8;
    bf16_t* sAp = sA + tid * 8;
    bf16_t* sBp = sB + tid * 8;

    floatx4 acc[4][4] = {};

    const int ra = wm * 64 + (lane & 15);   // A fragment row within tile
    const int rb = wn * 64 + (lane & 15);   // W fragment row within tile
    const int q  = lane >> 4;               // k-quad 0..3
    const int rx = lane & 7;                // (read row)&7 — 16i-invariant

    for (int kt = 0; kt < K; kt += 64) {
#pragma unroll
        for (int i = 0; i < 4; ++i) {
            GLD16(Ag + kt + (size_t)(32 * i) * K, sAp + i * 2048);
            GLD16(Wg + kt + (size_t)(32 * i) * K, sBp + i * 2048);
        }
        asm volatile("s_waitcnt vmcnt(0)" ::: "memory");
        __syncthreads();

#pragma unroll
        for (int ks = 0; ks < 2; ++ks) {
            const int c = ks * 4 + q;
            const int pc = (c ^ rx) * 8;    // physical chunk -> element offset
            bf16x8 af[4], bw[4];
#pragma unroll
            for (int i = 0; i < 4; ++i) {
                af[i] = *(const bf16x8*)(sA + (ra + i * 16) * 64 + pc);
                bw[i] = *(const bf16x8*)(sB + (rb + i * 16) * 64 + pc);
            }
#pragma unroll
            for (int mi = 0; mi < 4; ++mi)
#pragma unroll
                for (int ni = 0; ni < 4; ++ni)
                    acc[mi][ni] = __builtin_amdgcn_mfma_f32_16x16x32_bf16(
                        af[mi], bw[ni], acc[mi][ni], 0, 0, 0);
        }
        __syncthreads();
    }

    // epilogue: C/D layout col = lane&15, row = (lane>>4)*4 + reg
    const int row0 = tm + wm * 64 + (lane >> 4) * 4;
    const int col0 = tn + wn * 64 + (lane & 15);
#pragma unroll
    for (int ni = 0; ni < 4; ++ni) {
        const int col = col0 + ni * 16;
        const float bv = bias[col];
#pragma unroll
        for (int mi = 0; mi < 4; ++mi) {
#pragma unroll
            for (int r = 0; r < 4; ++r) {
                Vb[(size_t)(row0 + mi * 16 + r) * N + col] = f2bf(acc[mi][ni][r] + bv);
            }
        }
    }
}

// ---------------------------------------------------------------------------
// Fused multi-flow Householder: z row held in 32 VGPRs across nf flows.
// ONE WAVE PER ROW (no LDS, no __syncthreads). 256-thread block = 4 rows.
// Per flow: read V_f row (4 x bf16x8 per lane), butterfly shfl_xor reduce of
// vz and vv, update z in registers. Next flow's V row is prefetched before
// the reduce to hide HBM latency. Single z read + single z write total.
// Traffic for nf=8: 67(z) + 8*33.5(V) + 67(z) = 402 MB vs 1.2 GB unfused.
// v chunk j = elements 8*(lane+64j)..+8 <-> z4[2*(lane+64j)], z4[2*idx+1].
// ---------------------------------------------------------------------------
__global__ __launch_bounds__(256) void hflowN_kernel(
    const bf16_t* __restrict__ Vall,  // [nf][B, L]
    int nf,
    const float* __restrict__ zin, float* __restrict__ zout)
{
    const int lane = threadIdx.x & 63;
    const int row  = blockIdx.x * 4 + (threadIdx.x >> 6);
    const float4* z4 = (const float4*)(zin + (size_t)row * L_);
    float4*       zo = (float4*)(zout + (size_t)row * L_);

    float4 z[8];
#pragma unroll
    for (int j = 0; j < 4; ++j) {
        const int idx = lane + 64 * j;
        z[2 * j]     = z4[2 * idx];
        z[2 * j + 1] = z4[2 * idx + 1];
    }

    const size_t vstride = (size_t)B_ * L_;
    const bf16x8* v8 = (const bf16x8*)(Vall + (size_t)row * L_);

    bf16x8 vcur[4];
#pragma unroll
    for (int j = 0; j < 4; ++j) vcur[j] = v8[lane + 64 * j];

    for (int f = 0; f < nf; ++f) {
        bf16x8 vnxt[4];
        if (f + 1 < nf) {
            const bf16x8* vn = (const bf16x8*)((const bf16_t*)v8 + (size_t)(f + 1) * vstride);
#pragma unroll
            for (int j = 0; j < 4; ++j) vnxt[j] = vn[lane + 64 * j];
        }

        float vf[32];
#pragma unroll
        for (int j = 0; j < 4; ++j)
#pragma unroll
            for (int e = 0; e < 8; ++e) vf[j * 8 + e] = (float)vcur[j][e];

        float vz = 0.f, vv = 0.f;
#pragma unroll
        for (int j = 0; j < 4; ++j) {
            const float* fp = vf + j * 8;
            vz += fp[0] * z[2*j].x + fp[1] * z[2*j].y + fp[2] * z[2*j].z + fp[3] * z[2*j].w
                + fp[4] * z[2*j+1].x + fp[5] * z[2*j+1].y + fp[6] * z[2*j+1].z + fp[7] * z[2*j+1].w;
            vv += fp[0]*fp[0] + fp[1]*fp[1] + fp[2]*fp[2] + fp[3]*fp[3]
                + fp[4]*fp[4] + fp[5]*fp[5] + fp[6]*fp[6] + fp[7]*fp[7];
        }

#pragma unroll
        for (int off = 1; off < 64; off <<= 1) {
            vz += __shfl_xor(vz, off);
            vv += __shfl_xor(vv, off);
        }
        const float s = 2.0f * vz / vv;

#pragma unroll
        for (int j = 0; j < 4; ++j) {
            const float* fp = vf + j * 8;
            z[2*j].x -= s * fp[0]; z[2*j].y -= s * fp[1];
            z[2*j].z -= s * fp[2]; z[2*j].w -= s * fp[3];
            z[2*j+1].x -= s * fp[4]; z[2*j+1].y -= s * fp[5];
            z[2*j+1].z -= s * fp[6]; z[2*j+1].w -= s * fp[7];
        }

#pragma unroll
        for (int j = 0; j < 4; ++j) vcur[j] = vnxt[j];
    }

#pragma unroll
    for (int j = 0; j < 4; ++j) {
        const int idx = lane + 64 * j;
        zo[2 * idx]     = z[2 * j];
        zo[2 * idx + 1] = z[2 * j + 1];
    }
}

// ---------------------------------------------------------------------------
extern "C" void kernel_launch(void* const* d_in, const int* in_sizes, int n_in,
                              void* d_out, int out_size, void* d_ws, size_t ws_size,
                              hipStream_t stream) {
    (void)in_sizes; (void)n_in; (void)out_size;
    const float* z_in   = (const float*)d_in[0];  // [B, L]
    const float* h_last = (const float*)d_in[1];  // [B, H]
    const float* W0     = (const float*)d_in[2];  // [L, H]
    const float* b0     = (const float*)d_in[3];  // [L]
    const float* Wsp    = (const float*)d_in[4];  // [NF-1, L, L]
    const float* bsp    = (const float*)d_in[5];  // [NF-1, L]
    float* z_out = (float*)d_out;

    char* ws = (char*)d_ws;
    const size_t wbytes = (size_t)NF_ * L_ * L_ * 2;   // all 8 weights, bf16
    const size_t vbytes = (size_t)B_ * L_ * 2;         // one V matrix, bf16

    // bf16 weight conversion (common to both paths)
    bf16_t* Wbf = (bf16_t*)ws;
    cvt_kernel<<<(L_ * L_) / 1024, 256, 0, stream>>>(W0, Wbf);
    cvt_kernel<<<((NF_ - 1) * L_ * L_) / 1024, 256, 0, stream>>>(
        Wsp, Wbf + (size_t)L_ * L_);

    dim3 ggrid(L_ / 128, B_ / 128);

    if (ws_size >= wbytes + vbytes + (size_t)NF_ * vbytes) {
        // Fused path: weights | Hbf | V[0..7]. v-chain is z-independent, so
        // run all 8 GEMMs first, then ONE hflowN pass with z in registers.
        bf16_t* Hbf  = (bf16_t*)(ws + wbytes);
        bf16_t* Vall = Hbf + (size_t)B_ * L_;
        cvt_kernel<<<(B_ * L_) / 1024, 256, 0, stream>>>(h_last, Hbf);

        for (int j = 0; j < NF_; ++j) {
            const float* bias = (j == 0) ? b0 : bsp + (size_t)(j - 1) * L_;
            const bf16_t* Wj = Wbf + (size_t)j * L_ * L_;
            const bf16_t* Ain = (j == 0) ? Hbf : Vall + (size_t)(j - 1) * B_ * L_;
            bf16_t* Vout = Vall + (size_t)j * B_ * L_;
            gemm_bt_kernel<<<ggrid, 256, 0, stream>>>(Ain, Wj, bias, Vout);
        }
        hflowN_kernel<<<B_ / 4, 256, 0, stream>>>(Vall, NF_, z_in, z_out);
    } else {
        // Fallback (round-0 schedule): ping-pong V, per-flow reflection.
        bf16_t* Vp0 = (bf16_t*)(ws + wbytes);
        bf16_t* Vp1 = Vp0 + (size_t)B_ * L_;
        cvt_kernel<<<(B_ * L_) / 1024, 256, 0, stream>>>(h_last, Vp0);

        bf16_t* bufs[2] = { Vp0, Vp1 };
        for (int j = 0; j < NF_; ++j) {
            const float* bias = (j == 0) ? b0 : bsp + (size_t)(j - 1) * L_;
            const bf16_t* Wj = Wbf + (size_t)j * L_ * L_;
            bf16_t* Ain = bufs[j & 1];
            bf16_t* Vout = bufs[(j + 1) & 1];
            gemm_bt_kernel<<<ggrid, 256, 0, stream>>>(Ain, Wj, bias, Vout);
            hflowN_kernel<<<B_ / 4, 256, 0, stream>>>(
                Vout, 1, (j == 0) ? z_in : z_out, z_out);
        }
    }
}

// Round 3
// 854.058 us; speedup vs baseline: 1.3177x; 1.0411x over previous
//
#include <hip/hip_runtime.h>
#include <hip/hip_bf16.h>
#include <stdint.h>

// Problem constants (fixed by the reference file)
#define B_  8192
#define L_  2048
#define NF_ 8

typedef __bf16 bf16_t;
typedef __bf16 bf16x8 __attribute__((ext_vector_type(8)));
typedef __bf16 bf16x4 __attribute__((ext_vector_type(4)));
typedef float  floatx4 __attribute__((ext_vector_type(4)));

// fp32 -> bf16 round-to-nearest-even
__device__ __forceinline__ bf16_t f2bf(float f) {
    union { float f; uint32_t u; } a; a.f = f;
    uint32_t r = a.u + 0x7fffu + ((a.u >> 16) & 1u);
    union { uint16_t s; bf16_t b; } o; o.s = (uint16_t)(r >> 16);
    return o.b;
}

// async global->LDS, 16B per lane. LDS dest is wave-uniform base + lane*16.
#define GLD16(gp, lp)                                                          \
    __builtin_amdgcn_global_load_lds(                                          \
        (const __attribute__((address_space(1))) void*)(gp),                   \
        (__attribute__((address_space(3))) void*)(lp), 16, 0, 0)

// ---------------------------------------------------------------------------
// fp32 -> bf16 bulk conversion over three segments in one launch.
// Sizes in float4 units; grid-stride.
// ---------------------------------------------------------------------------
__global__ __launch_bounds__(256) void cvt3_kernel(
    const float* __restrict__ sa, bf16_t* __restrict__ da, int na,
    const float* __restrict__ sb, bf16_t* __restrict__ db, int nb,
    const float* __restrict__ sc, bf16_t* __restrict__ dc, int nc)
{
    const int total = na + nb + nc;
    for (int i = blockIdx.x * 256 + threadIdx.x; i < total;
         i += gridDim.x * 256) {
        const float* s; bf16_t* d; int j = i;
        if (j < na)            { s = sa; d = da; }
        else { j -= na;
            if (j < nb)        { s = sb; d = db; }
            else { j -= nb;      s = sc; d = dc; } }
        float4 f = ((const float4*)s)[j];
        bf16x4 o = { f2bf(f.x), f2bf(f.y), f2bf(f.z), f2bf(f.w) };
        ((bf16x4*)d)[j] = o;
    }
}

// ---------------------------------------------------------------------------
// Vb[M,N] = bf16( A[M,K] * W[N,K]^T + bias ).  M=8192, N=K=2048.
//
// 256x256 tile, 512 threads = 8 waves (2M x 4N), per-wave output 128x64
// (8 mi x 4 ni fragments of 16x16). BK=32: one MFMA covers a tile's K.
//
// RING OF 4 LDS SLOTS (slot = A[256][32] | B[256][32] = 32 KB; 128 KB total).
// Staging runs TWO TILES AHEAD: during tile t we stage tile t+2 into slot
// (t+2)&3, which is disjoint from slots t and t+1 -> race-free by slots.
// vmcnt invariant: at end of tile t, this tile issued <=4 loads (t+2's data);
// vmcnt(4) leaves at most those in flight and forces everything older
// (including tile t+1's data, staged during t-1) resident. Never 0 in the
// main loop. Epilogue: tile NT-2 stages nothing -> vmcnt(0) (drains NT-1's
// loads, issued 2 tiles earlier -> cheap); tile NT-1 no wait.
//
// 2 phases/tile, each {stage-half | ds_read -> barrier -> setprio 16 MFMA
// setprio -> barrier}. bw[4] loaded in phase A, reused in phase B.
// NO sched_barrier(0) anywhere (m141: pinning defeats the scheduler).
//
// LDS swizzle (rows of 4 x 16B chunks): logical chunk c of row r lives at
// physical c ^ ((r>>1)&3). 16-lane read groups (rows 0..15, fixed c) then
// spread over 4 bank-groups 2-way (free). global_load_lds writes linearly,
// so the GLOBAL source is pre-swizzled: staging thread tid covers physical
// slot tid (row tid>>2, phys chunk tid&3) -> logical chunk
// (tid&3)^((tid>>3)&3), invariant under the +128-row second load.
//
// XCD band swizzle (bijective over the 256-block 1D grid): XCD k owns
// M-tile band by in [4k, 4k+4) -> per-XCD A working set = 4 MB = its L2.
// ---------------------------------------------------------------------------
#define VM4  asm volatile("s_waitcnt vmcnt(4)" ::: "memory")
#define VM0  asm volatile("s_waitcnt vmcnt(0)" ::: "memory")
#define VMX  do {} while (0)

__global__ __launch_bounds__(512, 2) void gemm_bt_kernel(
    const bf16_t* __restrict__ A,   // [M, K]
    const bf16_t* __restrict__ W,   // [N, K]
    const float*  __restrict__ bias,// [N]
    bf16_t* __restrict__ Vb)        // [M, N] bf16 (also next A)
{
    constexpr int K  = L_;
    constexpr int N  = L_;
    constexpr int NT = K / 32;                   // 64 K-tiles
    __shared__ alignas(16) bf16_t lds[4][16384]; // slot: A[0..8191] B[8192..]

    const int tid  = threadIdx.x;
    const int lane = tid & 63;
    const int wave = tid >> 6;
    const int wm   = wave >> 2;   // 0..1
    const int wn   = wave & 3;    // 0..3

    // XCD band swizzle: grid is 1D 256 = (8 N-tiles) x (32 M-tiles)
    const int wg  = blockIdx.x;
    const int idx = wg >> 3;
    const int bx  = idx >> 2;                 // 0..7   N-tile
    const int by  = (wg & 7) * 4 + (idx & 3); // 0..31  M-tile
    const int tm  = by * 256;
    const int tn  = bx * 256;

    // --- staging addresses (pre-swizzled global source, linear LDS dest) ---
    const int r0 = tid >> 2;                          // 0..127
    const int lc = (tid & 3) ^ ((tid >> 3) & 3);      // logical chunk
    const bf16_t* Ag = A + (size_t)(tm + r0) * K + lc * 8;
    const bf16_t* Wg = W + (size_t)(tn + r0) * K + lc * 8;
    const int dA = tid * 8;
    const int dB = 8192 + tid * 8;

    // --- ds_read fragment offsets ---
    const int l15  = lane & 15;
    const int pc8  = (((lane >> 4) ^ ((l15 >> 1) & 3))) * 8; // phys chunk*8
    const int aBase = (wm * 128 + l15) * 32 + pc8;
    const int bBase = 8192 + (wn * 64 + l15) * 32 + pc8;

    floatx4 acc[8][4] = {};

    auto stageA = [&](int t) {
        bf16_t* d = &lds[t & 3][dA];
        const bf16_t* g = Ag + t * 32;
        GLD16(g, d);
        GLD16(g + (size_t)128 * K, d + 4096);
    };
    auto stageB = [&](int t) {
        bf16_t* d = &lds[t & 3][dB];
        const bf16_t* g = Wg + t * 32;
        GLD16(g, d);
        GLD16(g + (size_t)128 * K, d + 4096);
    };

    // prologue: tiles 0 and 1 staged; drain tile 0 (oldest 4), keep 1 in flight
    stageA(0); stageB(0);
    stageA(1); stageB(1);
    VM4;
    asm volatile("s_barrier" ::: "memory");

#define PHASE_MFMA(MB)                                                         \
    __builtin_amdgcn_s_setprio(1);                                             \
    _Pragma("unroll")                                                          \
    for (int mi = 0; mi < 4; ++mi)                                             \
        _Pragma("unroll")                                                      \
        for (int ni = 0; ni < 4; ++ni)                                         \
            acc[mi + (MB)][ni] = __builtin_amdgcn_mfma_f32_16x16x32_bf16(      \
                af[mi], bw[ni], acc[mi + (MB)][ni], 0, 0, 0);                  \
    __builtin_amdgcn_s_setprio(0);

#define TILE_BODY(T, STG, VMCB)                                                \
    {                                                                          \
        const bf16_t* sl = &lds[(T) & 3][0];                                   \
        bf16x8 af[4], bw[4];                                                   \
        /* phase A: stage A(t+2) | read bw + af[0..3] | barrier | 16 MFMA */   \
        if (STG) stageA((T) + 2);                                              \
        _Pragma("unroll")                                                      \
        for (int ni = 0; ni < 4; ++ni)                                         \
            bw[ni] = *(const bf16x8*)(sl + bBase + ni * 512);                  \
        _Pragma("unroll")                                                      \
        for (int mi = 0; mi < 4; ++mi)                                         \
            af[mi] = *(const bf16x8*)(sl + aBase + mi * 512);                  \
        asm volatile("s_barrier" ::: "memory");                                \
        PHASE_MFMA(0)                                                          \
        asm volatile("s_barrier" ::: "memory");                                \
        /* phase B: stage B(t+2) | read af[4..7] | barrier | 16 MFMA */        \
        if (STG) stageB((T) + 2);                                              \
        _Pragma("unroll")                                                      \
        for (int mi = 0; mi < 4; ++mi)                                         \
            af[mi] = *(const bf16x8*)(sl + aBase + (mi + 4) * 512);            \
        asm volatile("s_barrier" ::: "memory");                                \
        PHASE_MFMA(4)                                                          \
        VMCB;                                                                  \
        asm volatile("s_barrier" ::: "memory");                                \
    }

    for (int t = 0; t < NT - 2; ++t) TILE_BODY(t, 1, VM4);
    TILE_BODY(NT - 2, 0, VM0);
    TILE_BODY(NT - 1, 0, VMX);
#undef TILE_BODY
#undef PHASE_MFMA

    // epilogue: C/D layout col = lane&15, row = (lane>>4)*4 + reg.
    // Row-major store order: the 4 ni stores per row cover 128 contiguous
    // bytes -> full-line write combining.
    const int row0 = tm + wm * 128 + (lane >> 4) * 4;
    const int col0 = tn + wn * 64 + l15;
    float bv[4];
#pragma unroll
    for (int ni = 0; ni < 4; ++ni) bv[ni] = bias[col0 + ni * 16];
#pragma unroll
    for (int mi = 0; mi < 8; ++mi) {
#pragma unroll
        for (int r = 0; r < 4; ++r) {
            const size_t ro = (size_t)(row0 + mi * 16 + r) * N;
#pragma unroll
            for (int ni = 0; ni < 4; ++ni) {
                Vb[ro + col0 + ni * 16] = f2bf(acc[mi][ni][r] + bv[ni]);
            }
        }
    }
}

// ---------------------------------------------------------------------------
// Fused multi-flow Householder: z row held in 32 VGPRs across nf flows.
// ONE WAVE PER ROW. 256-thread block = 4 rows. Butterfly shfl_xor reduce.
// Next flow's V row prefetched before the reduce.
// ---------------------------------------------------------------------------
__global__ __launch_bounds__(256) void hflowN_kernel(
    const bf16_t* __restrict__ Vall,  // [nf][B, L]
    int nf,
    const float* __restrict__ zin, float* __restrict__ zout)
{
    const int lane = threadIdx.x & 63;
    const int row  = blockIdx.x * 4 + (threadIdx.x >> 6);
    const float4* z4 = (const float4*)(zin + (size_t)row * L_);
    float4*       zo = (float4*)(zout + (size_t)row * L_);

    float4 z[8];
#pragma unroll
    for (int j = 0; j < 4; ++j) {
        const int idx = lane + 64 * j;
        z[2 * j]     = z4[2 * idx];
        z[2 * j + 1] = z4[2 * idx + 1];
    }

    const size_t vstride = (size_t)B_ * L_;
    const bf16x8* v8 = (const bf16x8*)(Vall + (size_t)row * L_);

    bf16x8 vcur[4];
#pragma unroll
    for (int j = 0; j < 4; ++j) vcur[j] = v8[lane + 64 * j];

    for (int f = 0; f < nf; ++f) {
        bf16x8 vnxt[4];
        if (f + 1 < nf) {
            const bf16x8* vn = (const bf16x8*)((const bf16_t*)v8 + (size_t)(f + 1) * vstride);
#pragma unroll
            for (int j = 0; j < 4; ++j) vnxt[j] = vn[lane + 64 * j];
        }

        float vf[32];
#pragma unroll
        for (int j = 0; j < 4; ++j)
#pragma unroll
            for (int e = 0; e < 8; ++e) vf[j * 8 + e] = (float)vcur[j][e];

        float vz = 0.f, vv = 0.f;
#pragma unroll
        for (int j = 0; j < 4; ++j) {
            const float* fp = vf + j * 8;
            vz += fp[0] * z[2*j].x + fp[1] * z[2*j].y + fp[2] * z[2*j].z + fp[3] * z[2*j].w
                + fp[4] * z[2*j+1].x + fp[5] * z[2*j+1].y + fp[6] * z[2*j+1].z + fp[7] * z[2*j+1].w;
            vv += fp[0]*fp[0] + fp[1]*fp[1] + fp[2]*fp[2] + fp[3]*fp[3]
                + fp[4]*fp[4] + fp[5]*fp[5] + fp[6]*fp[6] + fp[7]*fp[7];
        }

#pragma unroll
        for (int off = 1; off < 64; off <<= 1) {
            vz += __shfl_xor(vz, off);
            vv += __shfl_xor(vv, off);
        }
        const float s = 2.0f * vz / vv;

#pragma unroll
        for (int j = 0; j < 4; ++j) {
            const float* fp = vf + j * 8;
            z[2*j].x -= s * fp[0]; z[2*j].y -= s * fp[1];
            z[2*j].z -= s * fp[2]; z[2*j].w -= s * fp[3];
            z[2*j+1].x -= s * fp[4]; z[2*j+1].y -= s * fp[5];
            z[2*j+1].z -= s * fp[6]; z[2*j+1].w -= s * fp[7];
        }

#pragma unroll
        for (int j = 0; j < 4; ++j) vcur[j] = vnxt[j];
    }

#pragma unroll
    for (int j = 0; j < 4; ++j) {
        const int idx = lane + 64 * j;
        zo[2 * idx]     = z[2 * j];
        zo[2 * idx + 1] = z[2 * j + 1];
    }
}

// ---------------------------------------------------------------------------
extern "C" void kernel_launch(void* const* d_in, const int* in_sizes, int n_in,
                              void* d_out, int out_size, void* d_ws, size_t ws_size,
                              hipStream_t stream) {
    (void)in_sizes; (void)n_in; (void)out_size;
    const float* z_in   = (const float*)d_in[0];  // [B, L]
    const float* h_last = (const float*)d_in[1];  // [B, H]
    const float* W0     = (const float*)d_in[2];  // [L, H]
    const float* b0     = (const float*)d_in[3];  // [L]
    const float* Wsp    = (const float*)d_in[4];  // [NF-1, L, L]
    const float* bsp    = (const float*)d_in[5];  // [NF-1, L]
    float* z_out = (float*)d_out;

    char* ws = (char*)d_ws;
    const size_t wbytes = (size_t)NF_ * L_ * L_ * 2;   // all 8 weights, bf16
    const size_t vbytes = (size_t)B_ * L_ * 2;         // one V matrix, bf16

    bf16_t* Wbf = (bf16_t*)ws;
    const int grid = 256;  // (L/256) * (B/256) with XCD band swizzle inside

    if (ws_size >= wbytes + vbytes + (size_t)NF_ * vbytes) {
        // Fused path: weights | Hbf | V[0..7]. v-chain is z-independent, so
        // run all 8 GEMMs first, then ONE hflowN pass with z in registers.
        bf16_t* Hbf  = (bf16_t*)(ws + wbytes);
        bf16_t* Vall = Hbf + (size_t)B_ * L_;

        cvt3_kernel<<<2048, 256, 0, stream>>>(
            W0, Wbf, (L_ * L_) / 4,
            Wsp, Wbf + (size_t)L_ * L_, ((NF_ - 1) * L_ * L_) / 4,
            h_last, Hbf, (B_ * L_) / 4);

        for (int j = 0; j < NF_; ++j) {
            const float* bias = (j == 0) ? b0 : bsp + (size_t)(j - 1) * L_;
            const bf16_t* Wj = Wbf + (size_t)j * L_ * L_;
            const bf16_t* Ain = (j == 0) ? Hbf : Vall + (size_t)(j - 1) * B_ * L_;
            bf16_t* Vout = Vall + (size_t)j * B_ * L_;
            gemm_bt_kernel<<<grid, 512, 0, stream>>>(Ain, Wj, bias, Vout);
        }
        hflowN_kernel<<<B_ / 4, 256, 0, stream>>>(Vall, NF_, z_in, z_out);
    } else {
        // Fallback: ping-pong V, per-flow reflection.
        bf16_t* Vp0 = (bf16_t*)(ws + wbytes);
        bf16_t* Vp1 = Vp0 + (size_t)B_ * L_;

        cvt3_kernel<<<2048, 256, 0, stream>>>(
            W0, Wbf, (L_ * L_) / 4,
            Wsp, Wbf + (size_t)L_ * L_, ((NF_ - 1) * L_ * L_) / 4,
            h_last, Vp0, (B_ * L_) / 4);

        bf16_t* bufs[2] = { Vp0, Vp1 };
        for (int j = 0; j < NF_; ++j) {
            const float* bias = (j == 0) ? b0 : bsp + (size_t)(j - 1) * L_;
            const bf16_t* Wj = Wbf + (size_t)j * L_ * L_;
            bf16_t* Ain = bufs[j & 1];
            bf16_t* Vout = bufs[(j + 1) & 1];
            gemm_bt_kernel<<<grid, 512, 0, stream>>>(Ain, Wj, bias, Vout);
            hflowN_kernel<<<B_ / 4, 256, 0, stream>>>(
                Vout, 1, (j == 0) ? z_in : z_out, z_out);
        }
    }
}